// Round 21
// baseline (116.747 us; speedup 1.0000x reference)
//
#include <hip/hip_runtime.h>

#define DM 1024
#define NH 16
#define TT 2048
#define BB 2
#define NTOK (BB*TT)
#define DQKV 3072

typedef __attribute__((ext_vector_type(8))) short bf16x8;   // 8 bf16 (4 VGPRs)
typedef __attribute__((ext_vector_type(4))) float f32x4;    // MFMA C/D 16x16
typedef __attribute__((ext_vector_type(4))) int  int4v;     // 16B chunk

static __device__ __forceinline__ short f2b(float f) {
  union { float f; unsigned u; } v; v.f = f;
  unsigned r = v.u + 0x7FFFu + ((v.u >> 16) & 1u);   // RNE fp32->bf16
  return (short)(r >> 16);
}

// ---------------- fp32 -> bf16 convert (x) ----------------
__global__ __launch_bounds__(256) void k_convert(const float* __restrict__ in,
                                                 short* __restrict__ out, int n) {
  int i = (blockIdx.x * 256 + threadIdx.x) * 8;
  if (i >= n) return;
  float4 a = *(const float4*)(in + i);
  float4 b = *(const float4*)(in + i + 4);
  bf16x8 o;
  o[0]=f2b(a.x); o[1]=f2b(a.y); o[2]=f2b(a.z); o[3]=f2b(a.w);
  o[4]=f2b(b.x); o[5]=f2b(b.y); o[6]=f2b(b.z); o[7]=f2b(b.w);
  *(bf16x8*)(out + i) = o;
}

// ---------------- all 4 weights [K][N] fp32 -> [N][K] bf16, one launch ----------------
__global__ __launch_bounds__(256) void k_transpose_w4(const float* __restrict__ Wq,
                                                      const float* __restrict__ Wk,
                                                      const float* __restrict__ Wv,
                                                      const float* __restrict__ Wo,
                                                      short* __restrict__ WqkvT,
                                                      short* __restrict__ WoT) {
  __shared__ short t[64][72];
  const int z = blockIdx.z;
  const float* W = (z == 0) ? Wq : (z == 1) ? Wk : (z == 2) ? Wv : Wo;
  short* Wt = (z < 3) ? WqkvT : WoT;
  const int row0 = (z < 3) ? z * 1024 : 0;
  int tid = threadIdx.x;
  int n0 = blockIdx.x * 64, k0 = blockIdx.y * 64;
  #pragma unroll
  for (int i = 0; i < 4; i++) {
    int id = tid + 256 * i;
    int r = id >> 4;        // k row within tile
    int c = id & 15;        // float4 chunk along n
    float4 v = *(const float4*)(W + (size_t)(k0 + r) * DM + n0 + c * 4);
    t[c*4+0][r] = f2b(v.x);
    t[c*4+1][r] = f2b(v.y);
    t[c*4+2][r] = f2b(v.z);
    t[c*4+3][r] = f2b(v.w);
  }
  __syncthreads();
  #pragma unroll
  for (int i = 0; i < 2; i++) {
    int id = tid + 256 * i;
    int r = id >> 3;        // n row
    int c = id & 7;         // 8-elem chunk along k
    bf16x8 o = *(const bf16x8*)&t[r][c * 8];
    *(bf16x8*)(Wt + (size_t)(row0 + n0 + r) * DM + k0 + c * 8) = o;
  }
}

// ---------------- GEMM NT: C[M][N] = A[M][K] * Bt[N][K]^T ----------------
// 16x16x32 MFMA, 2-phase double-buffered global_load_lds staging, G21
// involution swizzle, T1 XCD-chunked bijective remap, LDS roundtrip bf16
// epilogue; V-column blocks (n0 >= 2048) write directly into Vt (transposed +
// key-slot-permuted). BM templated: QKV uses BM=64 (32KB LDS -> 5 blocks/CU,
// latency-bound fix), out-proj BM=128.
template<int OUT_BF16, int BM, int BN>
__global__ __launch_bounds__(256) void k_gemm_lds(const short* __restrict__ A,
                                                  const short* __restrict__ Bt,
                                                  void* __restrict__ C,
                                                  int M, int N, int K,
                                                  int qcols, float qscale,
                                                  short* __restrict__ Vtout) {
  __shared__ short As[2][BM * 64];
  __shared__ short Bs[2][BN * 64];
  constexpr int MI = BM / 32;               // 16-row m-frags per wave
  constexpr int NI = BN / 32;               // 16-wide n-frags per wave
  const int tid = threadIdx.x;
  const int lane = tid & 63, w = tid >> 6;
  const int wm = w >> 1, wn = w & 1;        // 2x2 wave grid
  const int l15 = lane & 15, g = lane >> 4;
  const int nx = N / BN;
  const int cx = nx >> 3;
  const int bid = blockIdx.x;
  const int xcd = bid & 7, k_ = bid >> 3;
  const int bx = xcd * cx + (k_ % cx), by = k_ / cx;
  const int m0 = by * BM, n0 = bx * BN;
  const int srow = lane >> 3;               // 0..7 row within 8-row segment
  const int scol = ((lane & 7) ^ srow) * 8; // pre-swizzled SOURCE chunk (shorts)
  const int rsw = l15 & 7;                  // read-side XOR (row&7 == l15&7)

  auto stage = [&](int buf, int k0) {
    #pragma unroll
    for (int i = 0; i < BM / 32; i++) {
      int rbase = w * (BM / 4) + i * 8;
      __builtin_amdgcn_global_load_lds(
        (const __attribute__((address_space(1))) void*)(A + (size_t)(m0 + rbase + srow) * K + k0 + scol),
        (__attribute__((address_space(3))) void*)&As[buf][rbase * 64],
        16, 0, 0);
    }
    #pragma unroll
    for (int i = 0; i < BN / 32; i++) {
      int rbase = w * (BN / 4) + i * 8;
      __builtin_amdgcn_global_load_lds(
        (const __attribute__((address_space(1))) void*)(Bt + (size_t)(n0 + rbase + srow) * K + k0 + scol),
        (__attribute__((address_space(3))) void*)&Bs[buf][rbase * 64],
        16, 0, 0);
    }
  };

  f32x4 acc[MI][NI] = {};
  stage(0, 0);
  __syncthreads();                          // tile 0 resident
  const int nt = K / 64;
  for (int t = 0; t < nt; t++) {
    const int cur = t & 1;
    if (t + 1 < nt) stage(cur ^ 1, (t + 1) * 64);   // DMA in flight across compute
    #pragma unroll
    for (int kk = 0; kk < 64; kk += 32) {
      bf16x8 af[MI], bfr[NI];
      #pragma unroll
      for (int mi = 0; mi < MI; mi++)
        af[mi] = *(const bf16x8*)&As[cur][(wm * (BM / 2) + mi * 16 + l15) * 64 + ((((kk >> 3) + g) ^ rsw) << 3)];
      #pragma unroll
      for (int ni = 0; ni < NI; ni++)
        bfr[ni] = *(const bf16x8*)&Bs[cur][(wn * (BN / 2) + ni * 16 + l15) * 64 + ((((kk >> 3) + g) ^ rsw) << 3)];
      #pragma unroll
      for (int mi = 0; mi < MI; mi++)
        #pragma unroll
        for (int ni = 0; ni < NI; ni++)
          acc[mi][ni] = __builtin_amdgcn_mfma_f32_16x16x32_bf16(af[mi], bfr[ni], acc[mi][ni], 0, 0, 0);
    }
    __syncthreads();                        // drains next-tile DMA + protects cur
  }

  if (OUT_BF16) {
    if (Vtout != nullptr && n0 >= 2048) {
      // fused V epilogue: transpose + key-slot-permute into Vt [bh*64+d][t]
      constexpr int CH = BM / 8;             // 16B chunks per d-row
      short* Ct = &As[0][0];                 // [64 d][BM slot], granule XOR swz
      const int bIdx = m0 >> 11;             // batch (64 | 2048)
      const int t0b = m0 - bIdx * TT;
      const int bh = bIdx * NH + ((n0 - 2048) >> 6);
      #pragma unroll
      for (int mi = 0; mi < MI; mi++) {
        #pragma unroll
        for (int ni = 0; ni < NI; ni++) {
          #pragma unroll
          for (int j = 0; j < 4; j++) {
            int token = wm * (BM / 2) + mi * 16 + g * 4 + j;
            int d = wn * (BN / 2) + ni * 16 + l15;
            int tile = token >> 6, r = token & 63, n = r >> 4;
            int s = tile * 64 + (((n >> 1) << 5) | (((r >> 2) & 3) << 3) | ((n & 1) << 2) | (r & 3));
            int sp = (((s >> 3) ^ (d & (CH - 1))) << 3) | (s & 7);
            Ct[d * BM + sp] = f2b(acc[mi][ni][j]);
          }
        }
      }
      __syncthreads();
      #pragma unroll
      for (int u = tid; u < 64 * CH; u += 256) {   // 64 d-rows x CH chunks
        int d = u / CH, ch = u % CH;
        bf16x8 vv = *(const bf16x8*)&Ct[d * BM + ((ch ^ (d & (CH - 1))) << 3)];
        *(bf16x8*)(Vtout + (size_t)(bh * 64 + d) * TT + t0b + ch * 8) = vv;
      }
    } else {
      short* Cs = &As[0][0];
      #pragma unroll
      for (int mi = 0; mi < MI; mi++) {
        #pragma unroll
        for (int ni = 0; ni < NI; ni++) {
          #pragma unroll
          for (int j = 0; j < 4; j++) {
            int row = wm * (BM / 2) + mi * 16 + g * 4 + j;
            int col = wn * (BN / 2) + ni * 16 + l15;
            float v = acc[mi][ni][j];
            if (n0 + col < qcols) v *= qscale;   // wave-uniform (64 | qcols)
            Cs[row * BN + col] = f2b(v);
          }
        }
      }
      __syncthreads();
      constexpr int UNITS = BM * BN / 8;         // 16B chunks in the C tile
      #pragma unroll
      for (int u = tid; u < UNITS; u += 256) {
        int row = u / (BN / 8), ch = u % (BN / 8);
        bf16x8 vv = *(const bf16x8*)&Cs[row * BN + ch * 8];
        *(bf16x8*)((short*)C + (size_t)(m0 + row) * N + n0 + ch * 8) = vv;
      }
    }
  } else {
    #pragma unroll
    for (int mi = 0; mi < MI; mi++) {
      #pragma unroll
      for (int ni = 0; ni < NI; ni++) {
        #pragma unroll
        for (int j = 0; j < 4; j++) {
          int row = m0 + wm * (BM / 2) + mi * 16 + g * 4 + j;
          int col = n0 + wn * (BN / 2) + ni * 16 + l15;
          ((float*)C)[(size_t)row * N + col] = acc[mi][ni][j];
        }
      }
    }
  }
}

// ---------------- flash attention: 1024 blocks x 4 waves, 64-row q-tiles ----------------
// r18 verbatim (best measured: 52.6-54.8us): swapped QK^T, in-register P via
// key-slot-permuted Vt, accL via MFMA-ones, 32KB LDS, XCD-pinned bh, big-first.
__global__ __launch_bounds__(256) void k_attn(const short* __restrict__ Qkv,
                                              const short* __restrict__ Vt,
                                              short* __restrict__ Y) {
  __shared__ short Ks[2][64 * 64];
  __shared__ short Vs[2][64 * 64];
  const int tid = threadIdx.x;
  const int lane = tid & 63, w = tid >> 6;
  const int l15 = lane & 15, g = lane >> 4;
  const int bx = blockIdx.x;
  const int xcd = bx & 7, idx = bx >> 3;
  const int bh = xcd * 4 + (idx & 3);      // 4 (b,h) pinned per XCD
  const int b = bh >> 4, h = bh & 15;
  const int qt = 31 - (idx >> 2);          // 64-row q-tile, big-first
  const int q0 = qt * 64;
  const int nkt = qt + 1;
  const short* Qb = Qkv;                   // cols [0,1024), pre-scaled
  const short* Kb = Qkv + DM;              // cols [1024,2048)
  const int rsw = l15 & 7;                 // read-side chunk XOR (row&7 == l15&7)

  const bf16x8 vones = {0x3F80, 0x3F80, 0x3F80, 0x3F80, 0x3F80, 0x3F80, 0x3F80, 0x3F80};

  auto stage = [&](int buf, int kt) {
    #pragma unroll
    for (int i = 0; i < 2; i++) {
      int id = tid + 256 * i;
      int r = id >> 3;                     // row 0..63
      int cl = (id ^ r) & 7;               // source chunk = phys ^ (row&7)
      __builtin_amdgcn_global_load_lds(
        (const __attribute__((address_space(1))) void*)(Kb + (size_t)(b * TT + kt * 64 + r) * DQKV + h * 64 + cl * 8),
        (__attribute__((address_space(3))) void*)&Ks[buf][(w * 64 + 256 * i) * 8],
        16, 0, 0);
      __builtin_amdgcn_global_load_lds(
        (const __attribute__((address_space(1))) void*)(Vt + (size_t)(bh * 64 + r) * TT + kt * 64 + cl * 8),
        (__attribute__((address_space(3))) void*)&Vs[buf][(w * 64 + 256 * i) * 8],
        16, 0, 0);
    }
  };

  // Q fragments: rows q0 + w*16 + l15 (this lane's q-row), k = head dim
  bf16x8 aq[2];
  #pragma unroll
  for (int kc = 0; kc < 2; kc++)
    aq[kc] = *(const bf16x8*)(Qb + (size_t)(b * TT + q0 + w * 16 + l15) * DQKV + h * 64 + kc * 32 + 8 * g);

  f32x4 accO[4] = {};
  f32x4 accL = {};                         // MFMA-ones row sums
  float m2 = -1e30f;                       // running log2-max for q-row l15

  stage(0, 0);
  __syncthreads();

  for (int kt = 0; kt < nkt; kt++) {
    const int cur = kt & 1;
    if (kt + 1 < nkt) stage(cur ^ 1, kt + 1);

    // S^T(log2 units) = K Q^T: accS[n][j] = S[key = kt*64+n*16+g*4+j][q = l15]
    f32x4 accS[4] = {};
    __builtin_amdgcn_s_setprio(1);
    #pragma unroll
    for (int n = 0; n < 4; n++) {
      #pragma unroll
      for (int kc = 0; kc < 2; kc++) {
        bf16x8 bk = *(const bf16x8*)&Ks[cur][(n * 16 + l15) * 64 + (((kc * 4 + g) ^ rsw) << 3)];
        accS[n] = __builtin_amdgcn_mfma_f32_16x16x32_bf16(bk, aq[kc], accS[n], 0, 0, 0);
      }
    }
    __builtin_amdgcn_s_setprio(0);

    // causal mask (diag tile only) + in-lane max over this lane's 16 keys
    const int qg = q0 + w * 16 + l15;      // this lane's global q-row
    if (kt == qt) {                        // diagonal tile (block-uniform)
      #pragma unroll
      for (int n = 0; n < 4; n++) {
        #pragma unroll
        for (int j = 0; j < 4; j++) {
          int key = kt * 64 + n * 16 + g * 4 + j;
          if (key > qg) accS[n][j] = -1e30f;
        }
      }
    }
    float tmax = -1e30f;
    #pragma unroll
    for (int n = 0; n < 4; n++)
      #pragma unroll
      for (int j = 0; j < 4; j++)
        tmax = fmaxf(tmax, accS[n][j]);

    // T13 defer-max: rescale only when some lane's partial max exceeds m2+8
    if (!__all(tmax - m2 <= 8.0f)) {
      float t1 = fmaxf(tmax, __shfl_xor(tmax, 16));
      float full = fmaxf(t1, __shfl_xor(t1, 32));   // true max for q-row l15
      float mnew = fmaxf(m2, full);
      float al = exp2f(m2 - mnew);
      m2 = mnew;
      float alr[4];
      #pragma unroll
      for (int j = 0; j < 4; j++) alr[j] = __shfl(al, g * 4 + j);
      #pragma unroll
      for (int j = 0; j < 4; j++) accL[j] *= alr[j];
      #pragma unroll
      for (int n2 = 0; n2 < 4; n2++)
        #pragma unroll
        for (int j = 0; j < 4; j++) accO[n2][j] *= alr[j];
    }

    // p = 2^(s - m2), packed in-register into the lane's PV A-fragments:
    // slot(key n*16+g*4+j) = 32*(n>>1) + 8*g + 4*(n&1) + j  (matches Vt layout)
    unsigned cu[4][4];
    #pragma unroll
    for (int n = 0; n < 4; n++)
      #pragma unroll
      for (int j = 0; j < 4; j++) {
        union { float f; unsigned u; } cv;
        cv.f = exp2f(accS[n][j] - m2);
        cu[n][j] = cv.u;
      }

    __builtin_amdgcn_s_setprio(1);
    #pragma unroll
    for (int kc = 0; kc < 2; kc++) {
      union { int4v i; bf16x8 h; } pu;
      pu.i[0] = (int)((cu[2*kc+0][0] >> 16) | (cu[2*kc+0][1] & 0xFFFF0000u));
      pu.i[1] = (int)((cu[2*kc+0][2] >> 16) | (cu[2*kc+0][3] & 0xFFFF0000u));
      pu.i[2] = (int)((cu[2*kc+1][0] >> 16) | (cu[2*kc+1][1] & 0xFFFF0000u));
      pu.i[3] = (int)((cu[2*kc+1][2] >> 16) | (cu[2*kc+1][3] & 0xFFFF0000u));
      bf16x8 pa = pu.h;
      #pragma unroll
      for (int n2 = 0; n2 < 4; n2++) {
        bf16x8 vb = *(const bf16x8*)&Vs[cur][(n2 * 16 + l15) * 64 + (((kc * 4 + g) ^ rsw) << 3)];
        accO[n2] = __builtin_amdgcn_mfma_f32_16x16x32_bf16(pa, vb, accO[n2], 0, 0, 0);
      }
      accL = __builtin_amdgcn_mfma_f32_16x16x32_bf16(pa, vones, accL, 0, 0, 0);
    }
    __builtin_amdgcn_s_setprio(0);

    __syncthreads();                       // publishes prefetched buffer
  }

  // normalize (accL[j] = rowsum in every lane); Y via per-wave LDS scratch
  float inv[4];
  #pragma unroll
  for (int j = 0; j < 4; j++) inv[j] = 1.0f / accL[j];
  short* Ys = &Ks[0][w * 1024];            // 16 rows x 64 cols per wave
  #pragma unroll
  for (int n2 = 0; n2 < 4; n2++) {
    #pragma unroll
    for (int j = 0; j < 4; j++) {
      float v = accO[n2][j] * inv[j];
      Ys[(g * 4 + j) * 64 + n2 * 16 + l15] = f2b(v);
    }
  }
  const int orow = b * TT + q0 + w * 16;
  #pragma unroll
  for (int i = 0; i < 2; i++) {
    int unit = lane + 64 * i;
    int row = unit >> 3, ch = unit & 7;
    bf16x8 vv = *(const bf16x8*)&Ys[row * 64 + ch * 8];
    *(bf16x8*)(Y + (size_t)(orow + row) * DM + h * 64 + ch * 8) = vv;
  }
}

extern "C" void kernel_launch(void* const* d_in, const int* in_sizes, int n_in,
                              void* d_out, int out_size, void* d_ws, size_t ws_size,
                              hipStream_t stream) {
  const float* x  = (const float*)d_in[0];
  const float* Wq = (const float*)d_in[1];
  const float* Wk = (const float*)d_in[2];
  const float* Wv = (const float*)d_in[3];
  const float* Wo = (const float*)d_in[4];
  float* out = (float*)d_out;

  char* ws = (char*)d_ws;
  size_t off = 0;
  auto alloc = [&](size_t bytes) {
    char* p = ws + off;
    off += (bytes + 255) & ~(size_t)255;
    return p;
  };
  short* xb    = (short*)alloc((size_t)NTOK * DM * 2);    // also reused as Y
  short* WqkvT = (short*)alloc((size_t)DQKV * DM * 2);    // [3072][1024]
  short* WoT   = (short*)alloc((size_t)DM * DM * 2);
  short* Qkv   = (short*)alloc((size_t)NTOK * DQKV * 2);  // [4096][3072] (V cols unused)
  short* Vt    = (short*)alloc((size_t)NTOK * DM * 2);    // [32][64][2048]
  short* Yb    = xb;   // x dead after QKV GEMM; reuse region for Y
  if (off > ws_size) return;   // workspace too small -> loud failure

  k_convert<<<(NTOK * DM) / (256 * 8), 256, 0, stream>>>(x, xb, NTOK * DM);
  k_transpose_w4<<<dim3(DM / 64, DM / 64, 4), 256, 0, stream>>>(Wq, Wk, Wv, Wo, WqkvT, WoT);

  // fused QKV GEMM, BM=64 (32KB LDS -> 5 blocks/CU); Q cols pre-scaled by
  // 0.125*log2e; V cols written directly to Vt (transposed + slot-permuted).
  const float QSC = 0.125f * 1.44269504088896f;
  k_gemm_lds<1, 64, 64><<<dim3((DQKV / 64) * (NTOK / 64)), 256, 0, stream>>>(xb, WqkvT, Qkv, NTOK, DQKV, DM, DM, QSC, Vt);

  // attention: r18 structure (best measured)
  k_attn<<<dim3(1024), 256, 0, stream>>>(Qkv, Vt, Yb);

  // out projection, BM=128: fp32 out
  k_gemm_lds<0, 128, 64><<<dim3((DM / 64) * (NTOK / 128)), 256, 0, stream>>>(Yb, WoT, out, NTOK, DM, DM, 0, 1.0f, nullptr);
}

// Round 22
// 106.512 us; speedup vs baseline: 1.0961x; 1.0961x over previous
//
#include <hip/hip_runtime.h>

#define DM 1024
#define NH 16
#define TT 2048
#define BB 2
#define NTOK (BB*TT)
#define DQKV 3072

typedef __attribute__((ext_vector_type(8))) short bf16x8;   // 8 bf16 (4 VGPRs)
typedef __attribute__((ext_vector_type(4))) float f32x4;    // MFMA C/D 16x16
typedef __attribute__((ext_vector_type(4))) int  int4v;     // 16B chunk

static __device__ __forceinline__ short f2b(float f) {
  union { float f; unsigned u; } v; v.f = f;
  unsigned r = v.u + 0x7FFFu + ((v.u >> 16) & 1u);   // RNE fp32->bf16
  return (short)(r >> 16);
}

// ---------------- fused prep: weight transposes (z<4) + x fp32->bf16 (z>=4) ----------------
// z in [0,4): W[z] [K][N] fp32 -> [N][K] bf16 (WqkvT rows z*1024 / WoT).
// z in [4,12): x conversion, 256 blocks per slice x 2048 elems per block.
__global__ __launch_bounds__(256) void k_prep(const float* __restrict__ Wq,
                                              const float* __restrict__ Wk,
                                              const float* __restrict__ Wv,
                                              const float* __restrict__ Wo,
                                              short* __restrict__ WqkvT,
                                              short* __restrict__ WoT,
                                              const float* __restrict__ x,
                                              short* __restrict__ xb) {
  const int z = blockIdx.z;
  const int tid = threadIdx.x;
  if (z >= 4) {
    int blk = (z - 4) * 256 + blockIdx.y * 16 + blockIdx.x;   // 0..2047
    int i = (blk * 256 + tid) * 8;
    float4 a = *(const float4*)(x + i);
    float4 b = *(const float4*)(x + i + 4);
    bf16x8 o;
    o[0]=f2b(a.x); o[1]=f2b(a.y); o[2]=f2b(a.z); o[3]=f2b(a.w);
    o[4]=f2b(b.x); o[5]=f2b(b.y); o[6]=f2b(b.z); o[7]=f2b(b.w);
    *(bf16x8*)(xb + i) = o;
    return;
  }
  __shared__ short t[64][72];
  const float* W = (z == 0) ? Wq : (z == 1) ? Wk : (z == 2) ? Wv : Wo;
  short* Wt = (z < 3) ? WqkvT : WoT;
  const int row0 = (z < 3) ? z * 1024 : 0;
  int n0 = blockIdx.x * 64, k0 = blockIdx.y * 64;
  #pragma unroll
  for (int i = 0; i < 4; i++) {
    int id = tid + 256 * i;
    int r = id >> 4;        // k row within tile
    int c = id & 15;        // float4 chunk along n
    float4 v = *(const float4*)(W + (size_t)(k0 + r) * DM + n0 + c * 4);
    t[c*4+0][r] = f2b(v.x);
    t[c*4+1][r] = f2b(v.y);
    t[c*4+2][r] = f2b(v.z);
    t[c*4+3][r] = f2b(v.w);
  }
  __syncthreads();
  #pragma unroll
  for (int i = 0; i < 2; i++) {
    int id = tid + 256 * i;
    int r = id >> 3;        // n row
    int c = id & 7;         // 8-elem chunk along k
    bf16x8 o = *(const bf16x8*)&t[r][c * 8];
    *(bf16x8*)(Wt + (size_t)(row0 + n0 + r) * DM + k0 + c * 8) = o;
  }
}

// ---------------- GEMM NT: C[M][N] = A[M][K] * Bt[N][K]^T ----------------
// r18 structure: 16x16x32 MFMA, 2-phase double-buffered global_load_lds
// staging, G21 involution swizzle, T1 XCD-chunked bijective remap, LDS
// roundtrip bf16 epilogue; V-column blocks (n0 >= 2048) write directly into
// Vt (transposed + key-slot-permuted). BM=128/BN=64 measured optimum.
template<int OUT_BF16, int BM, int BN>
__global__ __launch_bounds__(256) void k_gemm_lds(const short* __restrict__ A,
                                                  const short* __restrict__ Bt,
                                                  void* __restrict__ C,
                                                  int M, int N, int K,
                                                  int qcols, float qscale,
                                                  short* __restrict__ Vtout) {
  __shared__ short As[2][BM * 64];
  __shared__ short Bs[2][BN * 64];
  constexpr int MI = BM / 32;               // 16-row m-frags per wave
  constexpr int NI = BN / 32;               // 16-wide n-frags per wave
  const int tid = threadIdx.x;
  const int lane = tid & 63, w = tid >> 6;
  const int wm = w >> 1, wn = w & 1;        // 2x2 wave grid
  const int l15 = lane & 15, g = lane >> 4;
  const int nx = N / BN;
  const int cx = nx >> 3;
  const int bid = blockIdx.x;
  const int xcd = bid & 7, k_ = bid >> 3;
  const int bx = xcd * cx + (k_ % cx), by = k_ / cx;
  const int m0 = by * BM, n0 = bx * BN;
  const int srow = lane >> 3;               // 0..7 row within 8-row segment
  const int scol = ((lane & 7) ^ srow) * 8; // pre-swizzled SOURCE chunk (shorts)
  const int rsw = l15 & 7;                  // read-side XOR (row&7 == l15&7)

  auto stage = [&](int buf, int k0) {
    #pragma unroll
    for (int i = 0; i < BM / 32; i++) {
      int rbase = w * (BM / 4) + i * 8;
      __builtin_amdgcn_global_load_lds(
        (const __attribute__((address_space(1))) void*)(A + (size_t)(m0 + rbase + srow) * K + k0 + scol),
        (__attribute__((address_space(3))) void*)&As[buf][rbase * 64],
        16, 0, 0);
    }
    #pragma unroll
    for (int i = 0; i < BN / 32; i++) {
      int rbase = w * (BN / 4) + i * 8;
      __builtin_amdgcn_global_load_lds(
        (const __attribute__((address_space(1))) void*)(Bt + (size_t)(n0 + rbase + srow) * K + k0 + scol),
        (__attribute__((address_space(3))) void*)&Bs[buf][rbase * 64],
        16, 0, 0);
    }
  };

  f32x4 acc[MI][NI] = {};
  stage(0, 0);
  __syncthreads();                          // tile 0 resident
  const int nt = K / 64;
  for (int t = 0; t < nt; t++) {
    const int cur = t & 1;
    if (t + 1 < nt) stage(cur ^ 1, (t + 1) * 64);   // DMA in flight across compute
    #pragma unroll
    for (int kk = 0; kk < 64; kk += 32) {
      bf16x8 af[MI], bfr[NI];
      #pragma unroll
      for (int mi = 0; mi < MI; mi++)
        af[mi] = *(const bf16x8*)&As[cur][(wm * (BM / 2) + mi * 16 + l15) * 64 + ((((kk >> 3) + g) ^ rsw) << 3)];
      #pragma unroll
      for (int ni = 0; ni < NI; ni++)
        bfr[ni] = *(const bf16x8*)&Bs[cur][(wn * (BN / 2) + ni * 16 + l15) * 64 + ((((kk >> 3) + g) ^ rsw) << 3)];
      #pragma unroll
      for (int mi = 0; mi < MI; mi++)
        #pragma unroll
        for (int ni = 0; ni < NI; ni++)
          acc[mi][ni] = __builtin_amdgcn_mfma_f32_16x16x32_bf16(af[mi], bfr[ni], acc[mi][ni], 0, 0, 0);
    }
    __syncthreads();                        // drains next-tile DMA + protects cur
  }

  if (OUT_BF16) {
    if (Vtout != nullptr && n0 >= 2048) {
      // fused V epilogue: transpose + key-slot-permute into Vt [bh*64+d][t]
      constexpr int CH = BM / 8;             // 16B chunks per d-row
      short* Ct = &As[0][0];                 // [64 d][BM slot], granule XOR swz
      const int bIdx = m0 >> 11;             // batch (128 | 2048)
      const int t0b = m0 - bIdx * TT;
      const int bh = bIdx * NH + ((n0 - 2048) >> 6);
      #pragma unroll
      for (int mi = 0; mi < MI; mi++) {
        #pragma unroll
        for (int ni = 0; ni < NI; ni++) {
          #pragma unroll
          for (int j = 0; j < 4; j++) {
            int token = wm * (BM / 2) + mi * 16 + g * 4 + j;
            int d = wn * (BN / 2) + ni * 16 + l15;
            int tile = token >> 6, r = token & 63, n = r >> 4;
            int s = tile * 64 + (((n >> 1) << 5) | (((r >> 2) & 3) << 3) | ((n & 1) << 2) | (r & 3));
            int sp = (((s >> 3) ^ (d & (CH - 1))) << 3) | (s & 7);
            Ct[d * BM + sp] = f2b(acc[mi][ni][j]);
          }
        }
      }
      __syncthreads();
      #pragma unroll
      for (int u = tid; u < 64 * CH; u += 256) {   // 64 d-rows x CH chunks
        int d = u / CH, ch = u % CH;
        bf16x8 vv = *(const bf16x8*)&Ct[d * BM + ((ch ^ (d & (CH - 1))) << 3)];
        *(bf16x8*)(Vtout + (size_t)(bh * 64 + d) * TT + t0b + ch * 8) = vv;
      }
    } else {
      short* Cs = &As[0][0];
      #pragma unroll
      for (int mi = 0; mi < MI; mi++) {
        #pragma unroll
        for (int ni = 0; ni < NI; ni++) {
          #pragma unroll
          for (int j = 0; j < 4; j++) {
            int row = wm * (BM / 2) + mi * 16 + g * 4 + j;
            int col = wn * (BN / 2) + ni * 16 + l15;
            float v = acc[mi][ni][j];
            if (n0 + col < qcols) v *= qscale;   // wave-uniform (64 | qcols)
            Cs[row * BN + col] = f2b(v);
          }
        }
      }
      __syncthreads();
      constexpr int UNITS = BM * BN / 8;         // 16B chunks in the C tile
      #pragma unroll
      for (int u = tid; u < UNITS; u += 256) {
        int row = u / (BN / 8), ch = u % (BN / 8);
        bf16x8 vv = *(const bf16x8*)&Cs[row * BN + ch * 8];
        *(bf16x8*)((short*)C + (size_t)(m0 + row) * N + n0 + ch * 8) = vv;
      }
    }
  } else {
    #pragma unroll
    for (int mi = 0; mi < MI; mi++) {
      #pragma unroll
      for (int ni = 0; ni < NI; ni++) {
        #pragma unroll
        for (int j = 0; j < 4; j++) {
          int row = m0 + wm * (BM / 2) + mi * 16 + g * 4 + j;
          int col = n0 + wn * (BN / 2) + ni * 16 + l15;
          ((float*)C)[(size_t)row * N + col] = acc[mi][ni][j];
        }
      }
    }
  }
}

// ---------------- flash attention: 1024 blocks x 4 waves, 64-row q-tiles ----------------
// r18 verbatim (best measured): swapped QK^T, in-register P via key-slot-
// permuted Vt, accL via MFMA-ones, 32KB LDS, XCD-pinned bh, big-first.
__global__ __launch_bounds__(256) void k_attn(const short* __restrict__ Qkv,
                                              const short* __restrict__ Vt,
                                              short* __restrict__ Y) {
  __shared__ short Ks[2][64 * 64];
  __shared__ short Vs[2][64 * 64];
  const int tid = threadIdx.x;
  const int lane = tid & 63, w = tid >> 6;
  const int l15 = lane & 15, g = lane >> 4;
  const int bx = blockIdx.x;
  const int xcd = bx & 7, idx = bx >> 3;
  const int bh = xcd * 4 + (idx & 3);      // 4 (b,h) pinned per XCD
  const int b = bh >> 4, h = bh & 15;
  const int qt = 31 - (idx >> 2);          // 64-row q-tile, big-first
  const int q0 = qt * 64;
  const int nkt = qt + 1;
  const short* Qb = Qkv;                   // cols [0,1024), pre-scaled
  const short* Kb = Qkv + DM;              // cols [1024,2048)
  const int rsw = l15 & 7;                 // read-side chunk XOR (row&7 == l15&7)

  const bf16x8 vones = {0x3F80, 0x3F80, 0x3F80, 0x3F80, 0x3F80, 0x3F80, 0x3F80, 0x3F80};

  auto stage = [&](int buf, int kt) {
    #pragma unroll
    for (int i = 0; i < 2; i++) {
      int id = tid + 256 * i;
      int r = id >> 3;                     // row 0..63
      int cl = (id ^ r) & 7;               // source chunk = phys ^ (row&7)
      __builtin_amdgcn_global_load_lds(
        (const __attribute__((address_space(1))) void*)(Kb + (size_t)(b * TT + kt * 64 + r) * DQKV + h * 64 + cl * 8),
        (__attribute__((address_space(3))) void*)&Ks[buf][(w * 64 + 256 * i) * 8],
        16, 0, 0);
      __builtin_amdgcn_global_load_lds(
        (const __attribute__((address_space(1))) void*)(Vt + (size_t)(bh * 64 + r) * TT + kt * 64 + cl * 8),
        (__attribute__((address_space(3))) void*)&Vs[buf][(w * 64 + 256 * i) * 8],
        16, 0, 0);
    }
  };

  // Q fragments: rows q0 + w*16 + l15 (this lane's q-row), k = head dim
  bf16x8 aq[2];
  #pragma unroll
  for (int kc = 0; kc < 2; kc++)
    aq[kc] = *(const bf16x8*)(Qb + (size_t)(b * TT + q0 + w * 16 + l15) * DQKV + h * 64 + kc * 32 + 8 * g);

  f32x4 accO[4] = {};
  f32x4 accL = {};                         // MFMA-ones row sums
  float m2 = -1e30f;                       // running log2-max for q-row l15

  stage(0, 0);
  __syncthreads();

  for (int kt = 0; kt < nkt; kt++) {
    const int cur = kt & 1;
    if (kt + 1 < nkt) stage(cur ^ 1, kt + 1);

    // S^T(log2 units) = K Q^T: accS[n][j] = S[key = kt*64+n*16+g*4+j][q = l15]
    f32x4 accS[4] = {};
    __builtin_amdgcn_s_setprio(1);
    #pragma unroll
    for (int n = 0; n < 4; n++) {
      #pragma unroll
      for (int kc = 0; kc < 2; kc++) {
        bf16x8 bk = *(const bf16x8*)&Ks[cur][(n * 16 + l15) * 64 + (((kc * 4 + g) ^ rsw) << 3)];
        accS[n] = __builtin_amdgcn_mfma_f32_16x16x32_bf16(bk, aq[kc], accS[n], 0, 0, 0);
      }
    }
    __builtin_amdgcn_s_setprio(0);

    // causal mask (diag tile only) + in-lane max over this lane's 16 keys
    const int qg = q0 + w * 16 + l15;      // this lane's global q-row
    if (kt == qt) {                        // diagonal tile (block-uniform)
      #pragma unroll
      for (int n = 0; n < 4; n++) {
        #pragma unroll
        for (int j = 0; j < 4; j++) {
          int key = kt * 64 + n * 16 + g * 4 + j;
          if (key > qg) accS[n][j] = -1e30f;
        }
      }
    }
    float tmax = -1e30f;
    #pragma unroll
    for (int n = 0; n < 4; n++)
      #pragma unroll
      for (int j = 0; j < 4; j++)
        tmax = fmaxf(tmax, accS[n][j]);

    // T13 defer-max: rescale only when some lane's partial max exceeds m2+8
    if (!__all(tmax - m2 <= 8.0f)) {
      float t1 = fmaxf(tmax, __shfl_xor(tmax, 16));
      float full = fmaxf(t1, __shfl_xor(t1, 32));   // true max for q-row l15
      float mnew = fmaxf(m2, full);
      float al = exp2f(m2 - mnew);
      m2 = mnew;
      float alr[4];
      #pragma unroll
      for (int j = 0; j < 4; j++) alr[j] = __shfl(al, g * 4 + j);
      #pragma unroll
      for (int j = 0; j < 4; j++) accL[j] *= alr[j];
      #pragma unroll
      for (int n2 = 0; n2 < 4; n2++)
        #pragma unroll
        for (int j = 0; j < 4; j++) accO[n2][j] *= alr[j];
    }

    // p = 2^(s - m2), packed in-register into the lane's PV A-fragments:
    // slot(key n*16+g*4+j) = 32*(n>>1) + 8*g + 4*(n&1) + j  (matches Vt layout)
    unsigned cu[4][4];
    #pragma unroll
    for (int n = 0; n < 4; n++)
      #pragma unroll
      for (int j = 0; j < 4; j++) {
        union { float f; unsigned u; } cv;
        cv.f = exp2f(accS[n][j] - m2);
        cu[n][j] = cv.u;
      }

    __builtin_amdgcn_s_setprio(1);
    #pragma unroll
    for (int kc = 0; kc < 2; kc++) {
      union { int4v i; bf16x8 h; } pu;
      pu.i[0] = (int)((cu[2*kc+0][0] >> 16) | (cu[2*kc+0][1] & 0xFFFF0000u));
      pu.i[1] = (int)((cu[2*kc+0][2] >> 16) | (cu[2*kc+0][3] & 0xFFFF0000u));
      pu.i[2] = (int)((cu[2*kc+1][0] >> 16) | (cu[2*kc+1][1] & 0xFFFF0000u));
      pu.i[3] = (int)((cu[2*kc+1][2] >> 16) | (cu[2*kc+1][3] & 0xFFFF0000u));
      bf16x8 pa = pu.h;
      #pragma unroll
      for (int n2 = 0; n2 < 4; n2++) {
        bf16x8 vb = *(const bf16x8*)&Vs[cur][(n2 * 16 + l15) * 64 + (((kc * 4 + g) ^ rsw) << 3)];
        accO[n2] = __builtin_amdgcn_mfma_f32_16x16x32_bf16(pa, vb, accO[n2], 0, 0, 0);
      }
      accL = __builtin_amdgcn_mfma_f32_16x16x32_bf16(pa, vones, accL, 0, 0, 0);
    }
    __builtin_amdgcn_s_setprio(0);

    __syncthreads();                       // publishes prefetched buffer
  }

  // normalize (accL[j] = rowsum in every lane); Y via per-wave LDS scratch
  float inv[4];
  #pragma unroll
  for (int j = 0; j < 4; j++) inv[j] = 1.0f / accL[j];
  short* Ys = &Ks[0][w * 1024];            // 16 rows x 64 cols per wave
  #pragma unroll
  for (int n2 = 0; n2 < 4; n2++) {
    #pragma unroll
    for (int j = 0; j < 4; j++) {
      float v = accO[n2][j] * inv[j];
      Ys[(g * 4 + j) * 64 + n2 * 16 + l15] = f2b(v);
    }
  }
  const int orow = b * TT + q0 + w * 16;
  #pragma unroll
  for (int i = 0; i < 2; i++) {
    int unit = lane + 64 * i;
    int row = unit >> 3, ch = unit & 7;
    bf16x8 vv = *(const bf16x8*)&Ys[row * 64 + ch * 8];
    *(bf16x8*)(Y + (size_t)(orow + row) * DM + h * 64 + ch * 8) = vv;
  }
}

extern "C" void kernel_launch(void* const* d_in, const int* in_sizes, int n_in,
                              void* d_out, int out_size, void* d_ws, size_t ws_size,
                              hipStream_t stream) {
  const float* x  = (const float*)d_in[0];
  const float* Wq = (const float*)d_in[1];
  const float* Wk = (const float*)d_in[2];
  const float* Wv = (const float*)d_in[3];
  const float* Wo = (const float*)d_in[4];
  float* out = (float*)d_out;

  char* ws = (char*)d_ws;
  size_t off = 0;
  auto alloc = [&](size_t bytes) {
    char* p = ws + off;
    off += (bytes + 255) & ~(size_t)255;
    return p;
  };
  short* xb    = (short*)alloc((size_t)NTOK * DM * 2);    // also reused as Y
  short* WqkvT = (short*)alloc((size_t)DQKV * DM * 2);    // [3072][1024]
  short* WoT   = (short*)alloc((size_t)DM * DM * 2);
  short* Qkv   = (short*)alloc((size_t)NTOK * DQKV * 2);  // [4096][3072] (V cols unused)
  short* Vt    = (short*)alloc((size_t)NTOK * DM * 2);    // [32][64][2048]
  short* Yb    = xb;   // x dead after QKV GEMM; reuse region for Y
  if (off > ws_size) return;   // workspace too small -> loud failure

  // fused prep: 4 weight transposes + x conversion in one launch
  k_prep<<<dim3(DM / 64, DM / 64, 12), 256, 0, stream>>>(Wq, Wk, Wv, Wo, WqkvT, WoT, x, xb);

  // fused QKV GEMM (BM=128/BN=64, measured optimum); Q cols pre-scaled by
  // 0.125*log2e; V cols written directly to Vt (transposed + slot-permuted).
  const float QSC = 0.125f * 1.44269504088896f;
  k_gemm_lds<1, 128, 64><<<dim3((DQKV / 64) * (NTOK / 128)), 256, 0, stream>>>(xb, WqkvT, Qkv, NTOK, DQKV, DM, DM, QSC, Vt);

  // attention: r18 structure (best measured)
  k_attn<<<dim3(1024), 256, 0, stream>>>(Qkv, Vt, Yb);

  // out projection: fp32 out
  k_gemm_lds<0, 128, 64><<<dim3((DM / 64) * (NTOK / 128)), 256, 0, stream>>>(Yb, WoT, out, NTOK, DM, DM, 0, 1.0f, nullptr);
}

// Round 23
// 105.918 us; speedup vs baseline: 1.1022x; 1.0056x over previous
//
#include <hip/hip_runtime.h>

#define DM 1024
#define NH 16
#define TT 2048
#define BB 2
#define NTOK (BB*TT)
#define DQKV 3072

typedef __attribute__((ext_vector_type(8))) short bf16x8;   // 8 bf16 (4 VGPRs)
typedef __attribute__((ext_vector_type(4))) float f32x4;    // MFMA C/D 16x16
typedef __attribute__((ext_vector_type(4))) int  int4v;     // 16B chunk

static __device__ __forceinline__ short f2b(float f) {
  union { float f; unsigned u; } v; v.f = f;
  unsigned r = v.u + 0x7FFFu + ((v.u >> 16) & 1u);   // RNE fp32->bf16
  return (short)(r >> 16);
}

// ---------------- fused prep: weight transposes (z<4) + x fp32->bf16 (z>=4) ----------------
__global__ __launch_bounds__(256) void k_prep(const float* __restrict__ Wq,
                                              const float* __restrict__ Wk,
                                              const float* __restrict__ Wv,
                                              const float* __restrict__ Wo,
                                              short* __restrict__ WqkvT,
                                              short* __restrict__ WoT,
                                              const float* __restrict__ x,
                                              short* __restrict__ xb) {
  const int z = blockIdx.z;
  const int tid = threadIdx.x;
  if (z >= 4) {
    int blk = (z - 4) * 256 + blockIdx.y * 16 + blockIdx.x;   // 0..2047
    int i = (blk * 256 + tid) * 8;
    float4 a = *(const float4*)(x + i);
    float4 b = *(const float4*)(x + i + 4);
    bf16x8 o;
    o[0]=f2b(a.x); o[1]=f2b(a.y); o[2]=f2b(a.z); o[3]=f2b(a.w);
    o[4]=f2b(b.x); o[5]=f2b(b.y); o[6]=f2b(b.z); o[7]=f2b(b.w);
    *(bf16x8*)(xb + i) = o;
    return;
  }
  __shared__ short t[64][72];
  const float* W = (z == 0) ? Wq : (z == 1) ? Wk : (z == 2) ? Wv : Wo;
  short* Wt = (z < 3) ? WqkvT : WoT;
  const int row0 = (z < 3) ? z * 1024 : 0;
  int n0 = blockIdx.x * 64, k0 = blockIdx.y * 64;
  #pragma unroll
  for (int i = 0; i < 4; i++) {
    int id = tid + 256 * i;
    int r = id >> 4;        // k row within tile
    int c = id & 15;        // float4 chunk along n
    float4 v = *(const float4*)(W + (size_t)(k0 + r) * DM + n0 + c * 4);
    t[c*4+0][r] = f2b(v.x);
    t[c*4+1][r] = f2b(v.y);
    t[c*4+2][r] = f2b(v.z);
    t[c*4+3][r] = f2b(v.w);
  }
  __syncthreads();
  #pragma unroll
  for (int i = 0; i < 2; i++) {
    int id = tid + 256 * i;
    int r = id >> 3;        // n row
    int c = id & 7;         // 8-elem chunk along k
    bf16x8 o = *(const bf16x8*)&t[r][c * 8];
    *(bf16x8*)(Wt + (size_t)(row0 + n0 + r) * DM + k0 + c * 8) = o;
  }
}

// ---------------- GEMM NT: C[M][N] = A[M][K] * Bt[N][K]^T ----------------
// r18 structure: 16x16x32 MFMA, 2-phase double-buffered global_load_lds
// staging, G21 involution swizzle, T1 XCD-chunked bijective remap, LDS
// roundtrip bf16 epilogue; V-column blocks (n0 >= 2048) write directly into
// Vt (transposed + key-slot-permuted). BM=128/BN=64 measured optimum.
template<int OUT_BF16, int BM, int BN>
__global__ __launch_bounds__(256) void k_gemm_lds(const short* __restrict__ A,
                                                  const short* __restrict__ Bt,
                                                  void* __restrict__ C,
                                                  int M, int N, int K,
                                                  int qcols, float qscale,
                                                  short* __restrict__ Vtout) {
  __shared__ short As[2][BM * 64];
  __shared__ short Bs[2][BN * 64];
  constexpr int MI = BM / 32;               // 16-row m-frags per wave
  constexpr int NI = BN / 32;               // 16-wide n-frags per wave
  const int tid = threadIdx.x;
  const int lane = tid & 63, w = tid >> 6;
  const int wm = w >> 1, wn = w & 1;        // 2x2 wave grid
  const int l15 = lane & 15, g = lane >> 4;
  const int nx = N / BN;
  const int cx = nx >> 3;
  const int bid = blockIdx.x;
  const int xcd = bid & 7, k_ = bid >> 3;
  const int bx = xcd * cx + (k_ % cx), by = k_ / cx;
  const int m0 = by * BM, n0 = bx * BN;
  const int srow = lane >> 3;               // 0..7 row within 8-row segment
  const int scol = ((lane & 7) ^ srow) * 8; // pre-swizzled SOURCE chunk (shorts)
  const int rsw = l15 & 7;                  // read-side XOR (row&7 == l15&7)

  auto stage = [&](int buf, int k0) {
    #pragma unroll
    for (int i = 0; i < BM / 32; i++) {
      int rbase = w * (BM / 4) + i * 8;
      __builtin_amdgcn_global_load_lds(
        (const __attribute__((address_space(1))) void*)(A + (size_t)(m0 + rbase + srow) * K + k0 + scol),
        (__attribute__((address_space(3))) void*)&As[buf][rbase * 64],
        16, 0, 0);
    }
    #pragma unroll
    for (int i = 0; i < BN / 32; i++) {
      int rbase = w * (BN / 4) + i * 8;
      __builtin_amdgcn_global_load_lds(
        (const __attribute__((address_space(1))) void*)(Bt + (size_t)(n0 + rbase + srow) * K + k0 + scol),
        (__attribute__((address_space(3))) void*)&Bs[buf][rbase * 64],
        16, 0, 0);
    }
  };

  f32x4 acc[MI][NI] = {};
  stage(0, 0);
  __syncthreads();                          // tile 0 resident
  const int nt = K / 64;
  for (int t = 0; t < nt; t++) {
    const int cur = t & 1;
    if (t + 1 < nt) stage(cur ^ 1, (t + 1) * 64);   // DMA in flight across compute
    #pragma unroll
    for (int kk = 0; kk < 64; kk += 32) {
      bf16x8 af[MI], bfr[NI];
      #pragma unroll
      for (int mi = 0; mi < MI; mi++)
        af[mi] = *(const bf16x8*)&As[cur][(wm * (BM / 2) + mi * 16 + l15) * 64 + ((((kk >> 3) + g) ^ rsw) << 3)];
      #pragma unroll
      for (int ni = 0; ni < NI; ni++)
        bfr[ni] = *(const bf16x8*)&Bs[cur][(wn * (BN / 2) + ni * 16 + l15) * 64 + ((((kk >> 3) + g) ^ rsw) << 3)];
      #pragma unroll
      for (int mi = 0; mi < MI; mi++)
        #pragma unroll
        for (int ni = 0; ni < NI; ni++)
          acc[mi][ni] = __builtin_amdgcn_mfma_f32_16x16x32_bf16(af[mi], bfr[ni], acc[mi][ni], 0, 0, 0);
    }
    __syncthreads();                        // drains next-tile DMA + protects cur
  }

  if (OUT_BF16) {
    if (Vtout != nullptr && n0 >= 2048) {
      // fused V epilogue: transpose + key-slot-permute into Vt [bh*64+d][t]
      constexpr int CH = BM / 8;             // 16B chunks per d-row
      short* Ct = &As[0][0];                 // [64 d][BM slot], granule XOR swz
      const int bIdx = m0 >> 11;             // batch (128 | 2048)
      const int t0b = m0 - bIdx * TT;
      const int bh = bIdx * NH + ((n0 - 2048) >> 6);
      #pragma unroll
      for (int mi = 0; mi < MI; mi++) {
        #pragma unroll
        for (int ni = 0; ni < NI; ni++) {
          #pragma unroll
          for (int j = 0; j < 4; j++) {
            int token = wm * (BM / 2) + mi * 16 + g * 4 + j;
            int d = wn * (BN / 2) + ni * 16 + l15;
            int tile = token >> 6, r = token & 63, n = r >> 4;
            int s = tile * 64 + (((n >> 1) << 5) | (((r >> 2) & 3) << 3) | ((n & 1) << 2) | (r & 3));
            int sp = (((s >> 3) ^ (d & (CH - 1))) << 3) | (s & 7);
            Ct[d * BM + sp] = f2b(acc[mi][ni][j]);
          }
        }
      }
      __syncthreads();
      #pragma unroll
      for (int u = tid; u < 64 * CH; u += 256) {   // 64 d-rows x CH chunks
        int d = u / CH, ch = u % CH;
        bf16x8 vv = *(const bf16x8*)&Ct[d * BM + ((ch ^ (d & (CH - 1))) << 3)];
        *(bf16x8*)(Vtout + (size_t)(bh * 64 + d) * TT + t0b + ch * 8) = vv;
      }
    } else {
      short* Cs = &As[0][0];
      #pragma unroll
      for (int mi = 0; mi < MI; mi++) {
        #pragma unroll
        for (int ni = 0; ni < NI; ni++) {
          #pragma unroll
          for (int j = 0; j < 4; j++) {
            int row = wm * (BM / 2) + mi * 16 + g * 4 + j;
            int col = wn * (BN / 2) + ni * 16 + l15;
            float v = acc[mi][ni][j];
            if (n0 + col < qcols) v *= qscale;   // wave-uniform (64 | qcols)
            Cs[row * BN + col] = f2b(v);
          }
        }
      }
      __syncthreads();
      constexpr int UNITS = BM * BN / 8;         // 16B chunks in the C tile
      #pragma unroll
      for (int u = tid; u < UNITS; u += 256) {
        int row = u / (BN / 8), ch = u % (BN / 8);
        bf16x8 vv = *(const bf16x8*)&Cs[row * BN + ch * 8];
        *(bf16x8*)((short*)C + (size_t)(m0 + row) * N + n0 + ch * 8) = vv;
      }
    }
  } else {
    #pragma unroll
    for (int mi = 0; mi < MI; mi++) {
      #pragma unroll
      for (int ni = 0; ni < NI; ni++) {
        #pragma unroll
        for (int j = 0; j < 4; j++) {
          int row = m0 + wm * (BM / 2) + mi * 16 + g * 4 + j;
          int col = n0 + wn * (BN / 2) + ni * 16 + l15;
          ((float*)C)[(size_t)row * N + col] = acc[mi][ni][j];
        }
      }
    }
  }
}

// ---------------- flash attention: 1024 blocks x 4 waves, 64-row q-tiles ----------------
// r18 structure + VALU micro-cuts: v_perm_b32 single-op bf16-pair packing
// (bit-identical to shift/and/or truncation) and pairwise tree row-max
// (fusable to v_max3). Swapped QK^T, in-register P via key-slot-permuted Vt,
// accL via MFMA-ones, 32KB LDS, XCD-pinned bh, big-first.
__global__ __launch_bounds__(256) void k_attn(const short* __restrict__ Qkv,
                                              const short* __restrict__ Vt,
                                              short* __restrict__ Y) {
  __shared__ short Ks[2][64 * 64];
  __shared__ short Vs[2][64 * 64];
  const int tid = threadIdx.x;
  const int lane = tid & 63, w = tid >> 6;
  const int l15 = lane & 15, g = lane >> 4;
  const int bx = blockIdx.x;
  const int xcd = bx & 7, idx = bx >> 3;
  const int bh = xcd * 4 + (idx & 3);      // 4 (b,h) pinned per XCD
  const int b = bh >> 4, h = bh & 15;
  const int qt = 31 - (idx >> 2);          // 64-row q-tile, big-first
  const int q0 = qt * 64;
  const int nkt = qt + 1;
  const short* Qb = Qkv;                   // cols [0,1024), pre-scaled
  const short* Kb = Qkv + DM;              // cols [1024,2048)
  const int rsw = l15 & 7;                 // read-side chunk XOR (row&7 == l15&7)

  const bf16x8 vones = {0x3F80, 0x3F80, 0x3F80, 0x3F80, 0x3F80, 0x3F80, 0x3F80, 0x3F80};

  auto stage = [&](int buf, int kt) {
    #pragma unroll
    for (int i = 0; i < 2; i++) {
      int id = tid + 256 * i;
      int r = id >> 3;                     // row 0..63
      int cl = (id ^ r) & 7;               // source chunk = phys ^ (row&7)
      __builtin_amdgcn_global_load_lds(
        (const __attribute__((address_space(1))) void*)(Kb + (size_t)(b * TT + kt * 64 + r) * DQKV + h * 64 + cl * 8),
        (__attribute__((address_space(3))) void*)&Ks[buf][(w * 64 + 256 * i) * 8],
        16, 0, 0);
      __builtin_amdgcn_global_load_lds(
        (const __attribute__((address_space(1))) void*)(Vt + (size_t)(bh * 64 + r) * TT + kt * 64 + cl * 8),
        (__attribute__((address_space(3))) void*)&Vs[buf][(w * 64 + 256 * i) * 8],
        16, 0, 0);
    }
  };

  // Q fragments: rows q0 + w*16 + l15 (this lane's q-row), k = head dim
  bf16x8 aq[2];
  #pragma unroll
  for (int kc = 0; kc < 2; kc++)
    aq[kc] = *(const bf16x8*)(Qb + (size_t)(b * TT + q0 + w * 16 + l15) * DQKV + h * 64 + kc * 32 + 8 * g);

  f32x4 accO[4] = {};
  f32x4 accL = {};                         // MFMA-ones row sums
  float m2 = -1e30f;                       // running log2-max for q-row l15

  stage(0, 0);
  __syncthreads();

  for (int kt = 0; kt < nkt; kt++) {
    const int cur = kt & 1;
    if (kt + 1 < nkt) stage(cur ^ 1, kt + 1);

    // S^T(log2 units) = K Q^T: accS[n][j] = S[key = kt*64+n*16+g*4+j][q = l15]
    f32x4 accS[4] = {};
    __builtin_amdgcn_s_setprio(1);
    #pragma unroll
    for (int n = 0; n < 4; n++) {
      #pragma unroll
      for (int kc = 0; kc < 2; kc++) {
        bf16x8 bk = *(const bf16x8*)&Ks[cur][(n * 16 + l15) * 64 + (((kc * 4 + g) ^ rsw) << 3)];
        accS[n] = __builtin_amdgcn_mfma_f32_16x16x32_bf16(bk, aq[kc], accS[n], 0, 0, 0);
      }
    }
    __builtin_amdgcn_s_setprio(0);

    // causal mask (diag tile only) + tree row-max over this lane's 16 keys
    const int qg = q0 + w * 16 + l15;      // this lane's global q-row
    if (kt == qt) {                        // diagonal tile (block-uniform)
      #pragma unroll
      for (int n = 0; n < 4; n++) {
        #pragma unroll
        for (int j = 0; j < 4; j++) {
          int key = kt * 64 + n * 16 + g * 4 + j;
          if (key > qg) accS[n][j] = -1e30f;
        }
      }
    }
    float mrow[4];
    #pragma unroll
    for (int n = 0; n < 4; n++)
      mrow[n] = fmaxf(fmaxf(accS[n][0], accS[n][1]), fmaxf(accS[n][2], accS[n][3]));
    float tmax = fmaxf(fmaxf(mrow[0], mrow[1]), fmaxf(mrow[2], mrow[3]));

    // T13 defer-max: rescale only when some lane's partial max exceeds m2+8
    if (!__all(tmax - m2 <= 8.0f)) {
      float t1 = fmaxf(tmax, __shfl_xor(tmax, 16));
      float full = fmaxf(t1, __shfl_xor(t1, 32));   // true max for q-row l15
      float mnew = fmaxf(m2, full);
      float al = exp2f(m2 - mnew);
      m2 = mnew;
      float alr[4];
      #pragma unroll
      for (int j = 0; j < 4; j++) alr[j] = __shfl(al, g * 4 + j);
      #pragma unroll
      for (int j = 0; j < 4; j++) accL[j] *= alr[j];
      #pragma unroll
      for (int n2 = 0; n2 < 4; n2++)
        #pragma unroll
        for (int j = 0; j < 4; j++) accO[n2][j] *= alr[j];
    }

    // p = 2^(s - m2), packed in-register into the lane's PV A-fragments:
    // slot(key n*16+g*4+j) = 32*(n>>1) + 8*g + 4*(n&1) + j  (matches Vt layout).
    // Pair-pack via v_perm_b32: (hi.u & 0xFFFF0000) | (lo.u >> 16), one op.
    unsigned cu[4][4];
    #pragma unroll
    for (int n = 0; n < 4; n++)
      #pragma unroll
      for (int j = 0; j < 4; j++) {
        union { float f; unsigned u; } cv;
        cv.f = exp2f(accS[n][j] - m2);
        cu[n][j] = cv.u;
      }

    __builtin_amdgcn_s_setprio(1);
    #pragma unroll
    for (int kc = 0; kc < 2; kc++) {
      union { int4v i; bf16x8 h; } pu;
      pu.i[0] = (int)__builtin_amdgcn_perm(cu[2*kc+0][1], cu[2*kc+0][0], 0x07060302u);
      pu.i[1] = (int)__builtin_amdgcn_perm(cu[2*kc+0][3], cu[2*kc+0][2], 0x07060302u);
      pu.i[2] = (int)__builtin_amdgcn_perm(cu[2*kc+1][1], cu[2*kc+1][0], 0x07060302u);
      pu.i[3] = (int)__builtin_amdgcn_perm(cu[2*kc+1][3], cu[2*kc+1][2], 0x07060302u);
      bf16x8 pa = pu.h;
      #pragma unroll
      for (int n2 = 0; n2 < 4; n2++) {
        bf16x8 vb = *(const bf16x8*)&Vs[cur][(n2 * 16 + l15) * 64 + (((kc * 4 + g) ^ rsw) << 3)];
        accO[n2] = __builtin_amdgcn_mfma_f32_16x16x32_bf16(pa, vb, accO[n2], 0, 0, 0);
      }
      accL = __builtin_amdgcn_mfma_f32_16x16x32_bf16(pa, vones, accL, 0, 0, 0);
    }
    __builtin_amdgcn_s_setprio(0);

    __syncthreads();                       // publishes prefetched buffer
  }

  // normalize (accL[j] = rowsum in every lane); Y via per-wave LDS scratch
  float inv[4];
  #pragma unroll
  for (int j = 0; j < 4; j++) inv[j] = 1.0f / accL[j];
  short* Ys = &Ks[0][w * 1024];            // 16 rows x 64 cols per wave
  #pragma unroll
  for (int n2 = 0; n2 < 4; n2++) {
    #pragma unroll
    for (int j = 0; j < 4; j++) {
      float v = accO[n2][j] * inv[j];
      Ys[(g * 4 + j) * 64 + n2 * 16 + l15] = f2b(v);
    }
  }
  const int orow = b * TT + q0 + w * 16;
  #pragma unroll
  for (int i = 0; i < 2; i++) {
    int unit = lane + 64 * i;
    int row = unit >> 3, ch = unit & 7;
    bf16x8 vv = *(const bf16x8*)&Ys[row * 64 + ch * 8];
    *(bf16x8*)(Y + (size_t)(orow + row) * DM + h * 64 + ch * 8) = vv;
  }
}

extern "C" void kernel_launch(void* const* d_in, const int* in_sizes, int n_in,
                              void* d_out, int out_size, void* d_ws, size_t ws_size,
                              hipStream_t stream) {
  const float* x  = (const float*)d_in[0];
  const float* Wq = (const float*)d_in[1];
  const float* Wk = (const float*)d_in[2];
  const float* Wv = (const float*)d_in[3];
  const float* Wo = (const float*)d_in[4];
  float* out = (float*)d_out;

  char* ws = (char*)d_ws;
  size_t off = 0;
  auto alloc = [&](size_t bytes) {
    char* p = ws + off;
    off += (bytes + 255) & ~(size_t)255;
    return p;
  };
  short* xb    = (short*)alloc((size_t)NTOK * DM * 2);    // also reused as Y
  short* WqkvT = (short*)alloc((size_t)DQKV * DM * 2);    // [3072][1024]
  short* WoT   = (short*)alloc((size_t)DM * DM * 2);
  short* Qkv   = (short*)alloc((size_t)NTOK * DQKV * 2);  // [4096][3072] (V cols unused)
  short* Vt    = (short*)alloc((size_t)NTOK * DM * 2);    // [32][64][2048]
  short* Yb    = xb;   // x dead after QKV GEMM; reuse region for Y
  if (off > ws_size) return;   // workspace too small -> loud failure

  // fused prep: 4 weight transposes + x conversion in one launch
  k_prep<<<dim3(DM / 64, DM / 64, 12), 256, 0, stream>>>(Wq, Wk, Wv, Wo, WqkvT, WoT, x, xb);

  // fused QKV GEMM (BM=128/BN=64); Q cols pre-scaled by 0.125*log2e; V cols
  // written directly to Vt (transposed + slot-permuted) in the epilogue.
  const float QSC = 0.125f * 1.44269504088896f;
  k_gemm_lds<1, 128, 64><<<dim3((DQKV / 64) * (NTOK / 128)), 256, 0, stream>>>(xb, WqkvT, Qkv, NTOK, DQKV, DM, DM, QSC, Vt);

  // attention: r18 structure + VALU micro-cuts
  k_attn<<<dim3(1024), 256, 0, stream>>>(Qkv, Vt, Yb);

  // out projection: fp32 out
  k_gemm_lds<0, 128, 64><<<dim3((DM / 64) * (NTOK / 128)), 256, 0, stream>>>(Yb, WoT, out, NTOK, DM, DM, 0, 1.0f, nullptr);
}